// Round 1
// baseline (294.499 us; speedup 1.0000x reference)
//
#include <hip/hip_runtime.h>
#include <hip/hip_bf16.h>

#define N_NODES 50000
#define N_EDGES 800000
#define D 128
#define GEMM_BN 64

// ---------------- CSR build ----------------

__global__ void hist_kernel(const int* __restrict__ dst, int* __restrict__ count) {
  int e = blockIdx.x * blockDim.x + threadIdx.x;
  if (e < N_EDGES) atomicAdd(&count[dst[e]], 1);
}

// Single-block chunked exclusive scan over N_NODES counts.
// Produces row_start[0..N] and a working copy in cursor[].
__global__ __launch_bounds__(1024) void scan_kernel(const int* __restrict__ count,
                                                    int* __restrict__ row_start,
                                                    int* __restrict__ cursor) {
  __shared__ int wsum[16];
  __shared__ int carry_s;
  int t = threadIdx.x;
  int lane = t & 63, wid = t >> 6;
  if (t == 0) carry_s = 0;
  __syncthreads();
  for (int base = 0; base < N_NODES; base += 1024) {
    int i = base + t;
    int x = (i < N_NODES) ? count[i] : 0;
    // wave-inclusive scan (wave64)
    int incl = x;
#pragma unroll
    for (int off = 1; off < 64; off <<= 1) {
      int y = __shfl_up(incl, off, 64);
      if (lane >= off) incl += y;
    }
    if (lane == 63) wsum[wid] = incl;
    int carry = carry_s;
    __syncthreads();
    if (t < 16) {
      int v = wsum[t];
      int s = v;
#pragma unroll
      for (int off = 1; off < 16; off <<= 1) {
        int y = __shfl_up(s, off, 64);
        if (t >= off) s += y;
      }
      wsum[t] = s - v;  // exclusive prefix of wave sums
    }
    __syncthreads();
    int excl = incl - x + wsum[wid] + carry;
    if (i < N_NODES) { row_start[i] = excl; cursor[i] = excl; }
    __syncthreads();
    if (t == 1023) carry_s = excl + x;  // running total
    __syncthreads();
  }
  if (t == 0) row_start[N_NODES] = carry_s;
}

__global__ void scatter_kernel(const int* __restrict__ src, const int* __restrict__ dst,
                               const float* __restrict__ w, int* __restrict__ cursor,
                               int* __restrict__ csr_src, float* __restrict__ csr_w) {
  int e = blockIdx.x * blockDim.x + threadIdx.x;
  if (e < N_EDGES) {
    int pos = atomicAdd(&cursor[dst[e]], 1);
    csr_src[pos] = src[e];
    csr_w[pos]   = w[e];
  }
}

// ---------------- aggregate: mean of h[src]*w by dst, then tanh ----------------
// One 128-thread block per node; lane owns one channel; register accumulate.
__global__ __launch_bounds__(128) void aggregate_kernel(const float* __restrict__ h,
                                                        const int* __restrict__ csr_src,
                                                        const float* __restrict__ csr_w,
                                                        const int* __restrict__ row_start,
                                                        float* __restrict__ hact) {
  int n = blockIdx.x;
  int lane = threadIdx.x;
  int beg = row_start[n], end = row_start[n + 1];
  float acc = 0.f;
  int e = beg;
  for (; e + 4 <= end; e += 4) {
    int   s0 = csr_src[e],   s1 = csr_src[e+1], s2 = csr_src[e+2], s3 = csr_src[e+3];
    float w0 = csr_w[e],     w1 = csr_w[e+1],   w2 = csr_w[e+2],   w3 = csr_w[e+3];
    float h0 = h[s0 * D + lane];
    float h1 = h[s1 * D + lane];
    float h2 = h[s2 * D + lane];
    float h3 = h[s3 * D + lane];
    acc = fmaf(h0, w0, acc);
    acc = fmaf(h1, w1, acc);
    acc = fmaf(h2, w2, acc);
    acc = fmaf(h3, w3, acc);
  }
  for (; e < end; ++e) acc = fmaf(h[csr_src[e] * D + lane], csr_w[e], acc);
  int deg = end - beg;
  float m = (deg > 0) ? acc / (float)deg : 0.f;
  hact[n * D + lane] = tanhf(m);
}

// ---------------- out = hact @ W^T + b (in-place through d_out) ----------------
// Block = 256 threads, 64 nodes. W + H tile staged in LDS with +1 pad
// (row stride 129 == 1 mod 32 -> conflict-free for both read patterns).
__global__ __launch_bounds__(256) void gemm_kernel(const float* __restrict__ hact,
                                                   const float* __restrict__ Wm,
                                                   const float* __restrict__ bias,
                                                   float* __restrict__ out) {
  __shared__ float Ws[D][D + 1];
  __shared__ float Hs[GEMM_BN][D + 1];
  int t = threadIdx.x;
  int n0 = blockIdx.x * GEMM_BN;
  for (int i = t; i < D * D; i += 256) Ws[i >> 7][i & 127] = Wm[i];
  for (int i = t; i < GEMM_BN * D; i += 256) {
    int r = i >> 7, c = i & 127;
    int n = n0 + r;
    Hs[r][c] = (n < N_NODES) ? hact[n * D + c] : 0.f;
  }
  __syncthreads();

  int tx = t & 15, ty = t >> 4;  // tx: j-group, ty: n-group (0..15)
  float acc[4][8];
#pragma unroll
  for (int i = 0; i < 4; ++i)
#pragma unroll
    for (int k = 0; k < 8; ++k) acc[i][k] = 0.f;

  for (int d = 0; d < D; ++d) {
    float hv[4], wv[8];
#pragma unroll
    for (int i = 0; i < 4; ++i) hv[i] = Hs[ty * 4 + i][d];
#pragma unroll
    for (int k = 0; k < 8; ++k) wv[k] = Ws[tx + 16 * k][d];
#pragma unroll
    for (int i = 0; i < 4; ++i)
#pragma unroll
      for (int k = 0; k < 8; ++k) acc[i][k] = fmaf(hv[i], wv[k], acc[i][k]);
  }

#pragma unroll
  for (int k = 0; k < 8; ++k) {
    float bj = bias[tx + 16 * k];
#pragma unroll
    for (int i = 0; i < 4; ++i) {
      int n = n0 + ty * 4 + i;
      if (n < N_NODES) out[n * D + tx + 16 * k] = acc[i][k] + bj;
    }
  }
}

extern "C" void kernel_launch(void* const* d_in, const int* in_sizes, int n_in,
                              void* d_out, int out_size, void* d_ws, size_t ws_size,
                              hipStream_t stream) {
  const float* h    = (const float*)d_in[0];
  const float* w    = (const float*)d_in[1];
  const int*   src  = (const int*)d_in[2];
  const int*   dst  = (const int*)d_in[3];
  const float* Wm   = (const float*)d_in[4];
  const float* bias = (const float*)d_in[5];
  float* out = (float*)d_out;

  // ws layout (all 16B-aligned):
  //   count:     N ints          @ 0
  //   row_start: N+1 ints        @ 200000
  //   cursor:    N ints          @ 400016
  //   csr_src:   E ints          @ 600016
  //   csr_w:     E floats        @ 3800016   (end = 7000016 bytes)
  char* ws = (char*)d_ws;
  int*   count     = (int*)(ws);
  int*   row_start = (int*)(ws + 200000);
  int*   cursor    = (int*)(ws + 400016);
  int*   csr_src   = (int*)(ws + 600016);
  float* csr_w     = (float*)(ws + 3800016);

  hipMemsetAsync(count, 0, N_NODES * sizeof(int), stream);
  hist_kernel<<<(N_EDGES + 255) / 256, 256, 0, stream>>>(dst, count);
  scan_kernel<<<1, 1024, 0, stream>>>(count, row_start, cursor);
  scatter_kernel<<<(N_EDGES + 255) / 256, 256, 0, stream>>>(src, dst, w, cursor, csr_src, csr_w);
  aggregate_kernel<<<N_NODES, 128, 0, stream>>>(h, csr_src, csr_w, row_start, out);
  gemm_kernel<<<(N_NODES + GEMM_BN - 1) / GEMM_BN, 256, 0, stream>>>(out, Wm, bias, out);
}